// Round 3
// baseline (86.943 us; speedup 1.0000x reference)
//
#include <hip/hip_runtime.h>

// CapsuleConv2d fused, MI355X gfx950. ALL I/O FP32.
// B=2, C_in=128 (G=8 x M=16), 32x32, 3x3 pad 1, O=16, L=16 -> C_out=256.
// k-means (dot) routing 3 iters + squash.
//
// v10 (3rd submit — rounds 1/2 died on container acquire, not the kernel;
// all accesses re-audited in-bounds):
// SINGLE fused kernel (v9 was prep[352blk] -> capsule[4096blk], two
// serialized dispatches; both kernels were below the 40us fill dispatches in
// the profile => overhead/structure-bound, not throughput-bound).
//  - A-frags: read 8 channels directly from x (8 x 4KB-strided dwords/lane,
//    L1/L2-resident; same values as old xT path, same mask, same hi/lo split).
//  - B-frags: per-block coalesced stage of the 18KB W tt-slice into LDS
//    padded [32][145] (bank = 17*lane%32, conflict-free gather), then per-lane
//    gather + identical trunc-bf16 hi/lo pack into registers (6 x i4/wave).
//    W LDS region aliases uLds; lifetime split by a barrier before CWR.
//  - No workspace, no prep, no fallback needed. Phase 2 identical to v9.

typedef float v2f __attribute__((ext_vector_type(2)));
typedef int   i4  __attribute__((ext_vector_type(4)));
typedef short bh8 __attribute__((ext_vector_type(8)));
typedef float f16v __attribute__((ext_vector_type(16)));

#define STR 34                         // u LDS row stride (floats)

#define DPP_ADD(a, ctrl)                                                     \
  a += __int_as_float(__builtin_amdgcn_update_dpp(                           \
          0, __float_as_int(a), ctrl, 0xF, 0xF, true))

__device__ __forceinline__ float dpp_add16(float x) {
    float s = x;
    DPP_ADD(s, 0x128); DPP_ADD(s, 0x124); DPP_ADD(s, 0x122); DPP_ADD(s, 0x121);
    return s;
}

__device__ __forceinline__ float swz16_add(float x) {
    // x + value from lane^16 within each 32-lane group
    int y = __builtin_amdgcn_ds_swizzle(__float_as_int(x), 0x401F);
    return x + __int_as_float(y);
}

__device__ __forceinline__ float frcp(float x) {
    return __builtin_amdgcn_rcpf(x);
}

__device__ __forceinline__ v2f pkfma(v2f a, v2f b, v2f c) {
    return __builtin_elementwise_fma(a, b, c);
}

// ---- B-fragment build: gather 8 W values from padded LDS slice + hi/lo pack
// Wlds (aliased at uLds[0]) layout: [t_loc 0..31][k*9+ij 0..143] stride 145.
// lane L: t_loc = L&31, k = (L>>5)*8 + j  ->  addr = wb + ij + 9*j,
// wb = (L&31)*145 + (L>>5)*72.  Banks: 17*L % 32 -> conflict-free.
#define BFRAG(BH, BL, IJ) {                                                  \
    float q0 = uLds[wb + (IJ)];                                              \
    float q1 = uLds[wb + (IJ) + 9];                                          \
    float q2 = uLds[wb + (IJ) + 18];                                         \
    float q3 = uLds[wb + (IJ) + 27];                                         \
    float q4 = uLds[wb + (IJ) + 36];                                         \
    float q5 = uLds[wb + (IJ) + 45];                                         \
    float q6 = uLds[wb + (IJ) + 54];                                         \
    float q7 = uLds[wb + (IJ) + 63];                                         \
    unsigned d0 = __float_as_uint(q0), d1 = __float_as_uint(q1);             \
    unsigned d2 = __float_as_uint(q2), d3 = __float_as_uint(q3);             \
    unsigned d4 = __float_as_uint(q4), d5 = __float_as_uint(q5);             \
    unsigned d6 = __float_as_uint(q6), d7 = __float_as_uint(q7);             \
    BH.x = (int)((d0 >> 16) | (d1 & 0xFFFF0000u));                           \
    BH.y = (int)((d2 >> 16) | (d3 & 0xFFFF0000u));                           \
    BH.z = (int)((d4 >> 16) | (d5 & 0xFFFF0000u));                           \
    BH.w = (int)((d6 >> 16) | (d7 & 0xFFFF0000u));                           \
    unsigned e0 = __float_as_uint(q0 - __uint_as_float(d0 & 0xFFFF0000u));   \
    unsigned e1 = __float_as_uint(q1 - __uint_as_float(d1 & 0xFFFF0000u));   \
    unsigned e2 = __float_as_uint(q2 - __uint_as_float(d2 & 0xFFFF0000u));   \
    unsigned e3 = __float_as_uint(q3 - __uint_as_float(d3 & 0xFFFF0000u));   \
    unsigned e4 = __float_as_uint(q4 - __uint_as_float(d4 & 0xFFFF0000u));   \
    unsigned e5 = __float_as_uint(q5 - __uint_as_float(d5 & 0xFFFF0000u));   \
    unsigned e6 = __float_as_uint(q6 - __uint_as_float(d6 & 0xFFFF0000u));   \
    unsigned e7 = __float_as_uint(q7 - __uint_as_float(d7 & 0xFFFF0000u));   \
    BL.x = (int)((e0 >> 16) | (e1 & 0xFFFF0000u));                           \
    BL.y = (int)((e2 >> 16) | (e3 & 0xFFFF0000u));                           \
    BL.z = (int)((e4 >> 16) | (e5 & 0xFFFF0000u));                           \
    BL.w = (int)((e6 >> 16) | (e7 & 0xFFFF0000u)); }

// ---- phase-1 macro: one ij tile -> MFMA -> u LDS ----
// C row r = (reg&3)+8*(reg>>2)+4*half: p=reg>>2 (CT), g=(reg&3)+4*half
#define CWR(REG, IJ)                                                         \
    uLds[wroff + STR * ((((REG) >> 2) * 72) + (((REG) & 3) * 9) + (IJ))] =   \
        acc[(REG)];

#define DO_IJ(IJ, BH, BL)                                                    \
  { const int di = (IJ) / 3, dj = (IJ) % 3;                                  \
    const int hh = h + di - 1;                                               \
    const bool hok = (unsigned)hh < 32u;                                     \
    const int hhc = hok ? hh : 0;                                            \
    const int ww = w0 + pl + dj - 1;                                         \
    const bool ok = hok && ((unsigned)ww < 32u);                             \
    const int wwc = ok ? ww : 0;                                             \
    const float* ap = x + bb * 131072 + (gl * 16 + half * 8) * 1024          \
                        + hhc * 32 + wwc;                                    \
    float f0 = ap[0],    f1 = ap[1024], f2 = ap[2048], f3 = ap[3072];        \
    float f4 = ap[4096], f5 = ap[5120], f6 = ap[6144], f7 = ap[7168];        \
    const float msk = ok ? 1.0f : 0.0f;                                      \
    f0 *= msk; f1 *= msk; f2 *= msk; f3 *= msk;                              \
    f4 *= msk; f5 *= msk; f6 *= msk; f7 *= msk;                              \
    unsigned b0 = __float_as_uint(f0), b1 = __float_as_uint(f1);             \
    unsigned b2 = __float_as_uint(f2), b3 = __float_as_uint(f3);             \
    unsigned b4 = __float_as_uint(f4), b5 = __float_as_uint(f5);             \
    unsigned b6 = __float_as_uint(f6), b7 = __float_as_uint(f7);             \
    i4 hp, lp;                                                               \
    hp.x = (int)((b0 >> 16) | (b1 & 0xFFFF0000u));                           \
    hp.y = (int)((b2 >> 16) | (b3 & 0xFFFF0000u));                           \
    hp.z = (int)((b4 >> 16) | (b5 & 0xFFFF0000u));                           \
    hp.w = (int)((b6 >> 16) | (b7 & 0xFFFF0000u));                           \
    unsigned l0 = __float_as_uint(f0 - __uint_as_float(b0 & 0xFFFF0000u));   \
    unsigned l1 = __float_as_uint(f1 - __uint_as_float(b1 & 0xFFFF0000u));   \
    unsigned l2 = __float_as_uint(f2 - __uint_as_float(b2 & 0xFFFF0000u));   \
    unsigned l3 = __float_as_uint(f3 - __uint_as_float(b3 & 0xFFFF0000u));   \
    unsigned l4 = __float_as_uint(f4 - __uint_as_float(b4 & 0xFFFF0000u));   \
    unsigned l5 = __float_as_uint(f5 - __uint_as_float(b5 & 0xFFFF0000u));   \
    unsigned l6 = __float_as_uint(f6 - __uint_as_float(b6 & 0xFFFF0000u));   \
    unsigned l7 = __float_as_uint(f7 - __uint_as_float(b7 & 0xFFFF0000u));   \
    lp.x = (int)((l0 >> 16) | (l1 & 0xFFFF0000u));                           \
    lp.y = (int)((l2 >> 16) | (l3 & 0xFFFF0000u));                           \
    lp.z = (int)((l4 >> 16) | (l5 & 0xFFFF0000u));                           \
    lp.w = (int)((l6 >> 16) | (l7 & 0xFFFF0000u));                           \
    bh8 aHi = __builtin_bit_cast(bh8, hp);                                   \
    bh8 aLo = __builtin_bit_cast(bh8, lp);                                   \
    bh8 bHi = __builtin_bit_cast(bh8, BH);                                   \
    bh8 bLo = __builtin_bit_cast(bh8, BL);                                   \
    f16v acc = {0.f,0.f,0.f,0.f,0.f,0.f,0.f,0.f,                             \
                0.f,0.f,0.f,0.f,0.f,0.f,0.f,0.f};                            \
    acc = __builtin_amdgcn_mfma_f32_32x32x16_bf16(aHi, bLo, acc, 0, 0, 0);   \
    acc = __builtin_amdgcn_mfma_f32_32x32x16_bf16(aLo, bHi, acc, 0, 0, 0);   \
    acc = __builtin_amdgcn_mfma_f32_32x32x16_bf16(aHi, bHi, acc, 0, 0, 0);   \
    CWR(0, IJ)  CWR(1, IJ)  CWR(2, IJ)  CWR(3, IJ)                           \
    CWR(4, IJ)  CWR(5, IJ)  CWR(6, IJ)  CWR(7, IJ)                           \
    CWR(8, IJ)  CWR(9, IJ)  CWR(10, IJ) CWR(11, IJ)                          \
    CWR(12, IJ) CWR(13, IJ) CWR(14, IJ) CWR(15, IJ) }

// ---- phase-2 macros (v8 lineage, 5 rows x 8 l per thread) ----
#define LROW(K)                                                              \
  { const v2f* r2_ = (const v2f*)(rb + (K) * 16 * STR);                      \
    U##K##0 = r2_[0]; U##K##1 = r2_[1]; U##K##2 = r2_[2]; U##K##3 = r2_[3]; }

#define DOTR(K)                                                              \
  ({ v2f d_ = U##K##0 * V0;                                                  \
     d_ = pkfma(U##K##1, V1, d_); d_ = pkfma(U##K##2, V2, d_);               \
     d_ = pkfma(U##K##3, V3, d_); swz16_add(d_.x + d_.y); })

#define MEANJ(J)                                                             \
  { v2f s_ = (U0##J + U1##J) + (U2##J + U3##J) + U4##J;                      \
    V##J.x = dpp_add16(s_.x) * (1.0f / 72.0f);                               \
    V##J.y = dpp_add16(s_.y) * (1.0f / 72.0f); }

#define UPDJ(J)                                                              \
  { v2f pv_ = e0v * U0##J;                                                   \
    pv_ = pkfma(e1v, U1##J, pv_); pv_ = pkfma(e2v, U2##J, pv_);              \
    pv_ = pkfma(e3v, U3##J, pv_); pv_ = pkfma(e4v, U4##J, pv_);              \
    V##J.x = dpp_add16(pv_.x) * rs;                                          \
    V##J.y = dpp_add16(pv_.y) * rs; }

// ---- main kernel v10: fully fused, no workspace ----
__global__ __launch_bounds__(256, 4)
void capsule_v10(const float* __restrict__ x, const float* __restrict__ W,
                 float* __restrict__ out) {
    __shared__ float uLds[4 * 72 * STR];     // 38.25 KB; front 4640 floats
                                             // double as padded W tt-slice
    const int blk = blockIdx.x;              // 4096
    const int tt = blk & 7;                  // t-tile (32 cols)
    const int q  = blk >> 3;                 // pixel quad
    const int bb = q >> 8;
    const int r  = q & 255;
    const int h  = r >> 3;
    const int w0 = (r & 7) << 2;
    const int tid = threadIdx.x;

    // ---- stage W tt-slice (18 KB, coalesced) into padded LDS [32][145] ----
    // flat i in [0,4608): t_loc = i/144, rem = i%144 -> addr = i + i/144
    {
        const float* gw = W + tt * 4608;
        #pragma unroll
        for (int rr = 0; rr < 18; ++rr) {
            int i = rr * 256 + tid;
            uLds[i + (i / 144)] = gw[i];
        }
    }
    __syncthreads();

    // ---- phase 1: build B-frags in regs, then MFMA priors ----
    {
        const int lane = tid & 63;
        const int wv   = tid >> 6;
        const int pl   = (lane & 31) >> 3;   // pixel within quad (A row>>3)
        const int gl   = lane & 7;           // group (A row&7)
        const int half = lane >> 5;          // k-half
        const int tl   = lane & 31;          // C col
        const int wroff = tl + STR * 9 * 4 * half;
        const int wb = (lane & 31) * 145 + (lane >> 5) * 72;

        i4 B0h = {0,0,0,0}, B0l = {0,0,0,0};
        i4 B1h = {0,0,0,0}, B1l = {0,0,0,0};
        i4 B2h = {0,0,0,0}, B2l = {0,0,0,0};
        if (wv == 0)      { BFRAG(B0h,B0l,0) BFRAG(B1h,B1l,4) BFRAG(B2h,B2l,8) }
        else if (wv == 1) { BFRAG(B0h,B0l,1) BFRAG(B1h,B1l,5) }
        else if (wv == 2) { BFRAG(B0h,B0l,2) BFRAG(B1h,B1l,6) }
        else              { BFRAG(B0h,B0l,3) BFRAG(B1h,B1l,7) }
        __syncthreads();   // all W gathers done; LDS becomes u-buffer

        if (wv == 0)      { DO_IJ(0,B0h,B0l) DO_IJ(4,B1h,B1l) DO_IJ(8,B2h,B2l) }
        else if (wv == 1) { DO_IJ(1,B0h,B0l) DO_IJ(5,B1h,B1l) }
        else if (wv == 2) { DO_IJ(2,B0h,B0l) DO_IJ(6,B1h,B1l) }
        else              { DO_IJ(3,B0h,B0l) DO_IJ(7,B1h,B1l) }
    }
    __syncthreads();

    // ---- phase 2: routing. wave = pixel; (o2, jh, sc) in-wave ----
    const int p  = tid >> 6;
    const int i6 = tid & 63;
    const int o2 = i6 >> 5;
    const int jh = (i6 >> 4) & 1;
    const int sc = i6 & 15;
    const bool has5 = (sc < 8);
    const float* rb = uLds + (p * 72 + sc) * STR + o2 * 16 + jh * 8;

    v2f U00, U01, U02, U03;
    v2f U10, U11, U12, U13;
    v2f U20, U21, U22, U23;
    v2f U30, U31, U32, U33;
    v2f U40, U41, U42, U43;
    U40 = U41 = U42 = U43 = (v2f){0.0f, 0.0f};
    LROW(0) LROW(1) LROW(2) LROW(3)
    if (has5) LROW(4)

    v2f V0, V1, V2, V3;
    MEANJ(0) MEANJ(1) MEANJ(2) MEANJ(3)

    #pragma unroll 1
    for (int it = 0; it < 3; ++it) {
        v2f ssv = V0 * V0;
        ssv = pkfma(V1, V1, ssv); ssv = pkfma(V2, V2, ssv);
        ssv = pkfma(V3, V3, ssv);
        float ss = swz16_add(ssv.x + ssv.y);
        float inv = frcp(fmaxf(sqrtf(ss), 1e-12f));

        float E0 = __expf(DOTR(0) * inv);
        float E1 = __expf(DOTR(1) * inv);
        float E2 = __expf(DOTR(2) * inv);
        float E3 = __expf(DOTR(3) * inv);
        float E4 = has5 ? __expf(DOTR(4) * inv) : 0.0f;
        float ssum = dpp_add16(((E0 + E1) + (E2 + E3)) + E4);
        float rs = frcp(ssum);

        v2f e0v = {E0, E0}, e1v = {E1, E1}, e2v = {E2, E2};
        v2f e3v = {E3, E3}, e4v = {E4, E4};
        UPDJ(0) UPDJ(1) UPDJ(2) UPDJ(3)
    }

    v2f ssv = V0 * V0;
    ssv = pkfma(V1, V1, ssv); ssv = pkfma(V2, V2, ssv);
    ssv = pkfma(V3, V3, ssv);
    float ss = swz16_add(ssv.x + ssv.y);
    float scale = sqrtf(ss) * frcp(1.0f + ss);

    v2f aa0 = (sc & 4) ? V2 : V0;
    v2f aa1 = (sc & 4) ? V3 : V1;
    v2f bb0 = (sc & 2) ? aa1 : aa0;
    float res = ((sc & 1) ? bb0.y : bb0.x) * scale;
    if (sc < 8) {
        int tg = tt * 32 + o2 * 16 + jh * 8 + sc;   // global channel
        out[((bb * 256 + tg) * 32 + h) * 32 + w0 + p] = res;
    }
}

extern "C" void kernel_launch(void* const* d_in, const int* in_sizes, int n_in,
                              void* d_out, int out_size, void* d_ws, size_t ws_size,
                              hipStream_t stream) {
    const float* x = (const float*)d_in[0];   // [2,128,32,32]
    const float* W = (const float*)d_in[1];   // [16,16,16,3,3]
    float* out = (float*)d_out;               // [2,256,32,32]
    (void)d_ws; (void)ws_size; (void)in_sizes; (void)n_in; (void)out_size;
    capsule_v10<<<4096, 256, 0, stream>>>(x, W, out);
}